// Round 13
// baseline (51.432 us; speedup 1.0000x reference)
//
#include <hip/hip_runtime.h>

#define K 5
#define N_ 8
#define C_ 256
#define H_ 64
#define W_ 64
#define HW (H_ * W_)
#define HO 128
#define WO 128
#define HOWO (HO * WO)
#define HB 4              // base rows per block (full width)
#define CCHUNK 32         // channels per block
#define UC 8              // channels per stage group (2 float4 slabs)
#define NGROUP (CCHUNK / UC)      // 4
#define LDS_R (HB + K - 1)        // 8 halo rows
#define LDS_C 68                  // 64 cols + 2 pad each side (zero-filled)
#define POS (LDS_R * LDS_C)       // 544

typedef __attribute__((ext_vector_type(2))) float f2;

__global__ __launch_bounds__(256)
void carafe_row_kernel(const float* __restrict__ feat,
                       const float* __restrict__ mask,
                       float* __restrict__ out) {
    const int ht = blockIdx.x;       // 0..15
    const int zc = blockIdx.y;       // 0..63 (n*8 + chunk)
    const int n  = zc >> 3;
    const int c0 = (zc & 7) * CCHUNK;
    const int h0 = ht * HB;

    const int tid = threadIdx.x;
    const int r   = tid >> 6;        // 0..3  base row (one wave = one row)
    const int c   = tid & 63;        // 0..63 base col (full width)
    const int hb  = h0 + r;

    // Channel-invariant masks for this thread's 2x2 output quad (f2 over b).
    f2 m0[K * K], m1[K * K];
    {
        const f2* mb = (const f2*)(mask + (size_t)n * (K * K) * HOWO
                                        + (size_t)(2 * hb) * WO + 2 * c);
        #pragma unroll
        for (int i = 0; i < K * K; ++i) {
            m0[i] = mb[(size_t)i * (HOWO / 2)];            // a = 0
            m1[i] = mb[(size_t)i * (HOWO / 2) + WO / 2];   // a = 1
        }
    }

    // Staging geometry: halo positions tid, tid+256, tid+512 (if < POS).
    int off[3]; bool val[3];
    #pragma unroll
    for (int i = 0; i < 3; ++i) {
        int p  = tid + i * 256;
        int rr = p / LDS_C, cc = p - rr * LDS_C;
        int hs = h0 - 2 + rr;
        int ws = cc - 2;
        val[i] = (p < POS) && (hs >= 0) && (hs < H_) && (ws >= 0) && (ws < W_);
        off[i] = hs * W_ + ws;
    }

    // Channel-interleaved halo tile: [buf][slab of 4ch][pos] float4. 34816 B.
    __shared__ float4 lds[2][2][POS];

    const float* fbase = feat + (size_t)n * C_ * HW;
    float*       obase = out  + (size_t)n * C_ * HOWO
                              + (size_t)(2 * hb) * WO + 2 * c;

    // Depth-1 staging, single register set, all indices static.
    float sreg[3][UC];
    auto stage_load = [&](int cbase) {
        const float* fp = fbase + (size_t)cbase * HW;
        #pragma unroll
        for (int i = 0; i < 3; ++i)
            #pragma unroll
            for (int u = 0; u < UC; ++u)
                sreg[i][u] = val[i] ? fp[u * HW + off[i]] : 0.f;
    };
    auto stage_write = [&](int buf) {
        #pragma unroll
        for (int i = 0; i < 3; ++i) {
            int p = tid + i * 256;
            if (p < POS) {
                lds[buf][0][p] = make_float4(sreg[i][0], sreg[i][1],
                                             sreg[i][2], sreg[i][3]);
                lds[buf][1][p] = make_float4(sreg[i][4], sreg[i][5],
                                             sreg[i][6], sreg[i][7]);
            }
        }
    };

    stage_load(c0);
    stage_write(0);
    __syncthreads();

    const int rbase = r * LDS_C + c;

    for (int g = 0; g < NGROUP; ++g) {
        const int buf = g & 1;

        // T14: issue next group's global loads before compute.
        if (g + 1 < NGROUP) stage_load(c0 + (g + 1) * UC);

        // Compute the group's 16 outputs into registers (held across barrier).
        f2 a0[2][4], a1[2][4];
        #pragma unroll
        for (int ss = 0; ss < 2; ++ss) {
            const float4* Ls = &lds[buf][ss][rbase];
            #pragma unroll
            for (int u = 0; u < 4; ++u) { a0[ss][u] = (f2)0.f; a1[ss][u] = (f2)0.f; }
            #pragma unroll
            for (int ki = 0; ki < K; ++ki) {
                #pragma unroll
                for (int kj = 0; kj < K; ++kj) {
                    float4 f  = Ls[ki * LDS_C + kj];   // 1 ds_read_b128 -> 16 FMA
                    f2 w0m = m0[ki * K + kj];
                    f2 w1m = m1[ki * K + kj];
                    a0[ss][0] += f.x * w0m;  a1[ss][0] += f.x * w1m;
                    a0[ss][1] += f.y * w0m;  a1[ss][1] += f.y * w1m;
                    a0[ss][2] += f.z * w0m;  a1[ss][2] += f.z * w1m;
                    a0[ss][3] += f.w * w0m;  a1[ss][3] += f.w * w1m;
                }
            }
        }

        // Publish next group's LDS and cross the barrier BEFORE storing:
        // at the vmcnt(0) drain preceding s_barrier, the only outstanding
        // stores are from the PREVIOUS group (a full compute phase old ->
        // retired), so the drain is ~free. In R9's order the 16 fresh nt
        // stores stalled every group boundary by ~store-ack latency.
        if (g + 1 < NGROUP) {
            stage_write(buf ^ 1);
            __syncthreads();
        }

        // Fire-and-forget stores after the barrier. One wave = one base
        // row: each store covers a full aligned 512B output row.
        #pragma unroll
        for (int ss = 0; ss < 2; ++ss)
            #pragma unroll
            for (int u = 0; u < 4; ++u) {
                f2* op = (f2*)(obase + (size_t)(c0 + g * UC + ss * 4 + u) * HOWO);
                __builtin_nontemporal_store(a0[ss][u], op);            // row 2hb
                __builtin_nontemporal_store(a1[ss][u], op + WO / 2);   // row 2hb+1
            }
    }
}

extern "C" void kernel_launch(void* const* d_in, const int* in_sizes, int n_in,
                              void* d_out, int out_size, void* d_ws, size_t ws_size,
                              hipStream_t stream) {
    const float* feat = (const float*)d_in[0];
    const float* mask = (const float*)d_in[1];
    float* out = (float*)d_out;

    dim3 grid(H_ / HB, N_ * (C_ / CCHUNK));  // (16, 64) = 1024 blocks
    dim3 block(256);
    carafe_row_kernel<<<grid, block, 0, stream>>>(feat, mask, out);
}

// Round 14
// 45.648 us; speedup vs baseline: 1.1267x; 1.1267x over previous
//
#include <hip/hip_runtime.h>

#define K 5
#define N_ 8
#define C_ 256
#define H_ 64
#define W_ 64
#define HW (H_ * W_)
#define HO 128
#define WO 128
#define HOWO (HO * WO)
#define HB 4              // base rows per block (full width)
#define CCHUNK 32         // channels per block
#define UC 4              // channels per stage group (ONE float4 slab)
#define NGROUP (CCHUNK / UC)      // 8
#define LDS_R (HB + K - 1)        // 8 halo rows
#define LDS_C 68                  // 64 cols + 2 pad each side (zero-filled)
#define POS (LDS_R * LDS_C)       // 544

typedef __attribute__((ext_vector_type(2))) float f2;

__global__ __launch_bounds__(256)
void carafe_row_kernel(const float* __restrict__ feat,
                       const float* __restrict__ mask,
                       float* __restrict__ out) {
    const int ht = blockIdx.x;       // 0..15
    const int zc = blockIdx.y;       // 0..63 (n*8 + chunk)
    const int n  = zc >> 3;
    const int c0 = (zc & 7) * CCHUNK;
    const int h0 = ht * HB;

    const int tid = threadIdx.x;
    const int r   = tid >> 6;        // 0..3  base row (one wave = one row)
    const int c   = tid & 63;        // 0..63 base col (full width)
    const int hb  = h0 + r;

    // Channel-invariant masks for this thread's 2x2 output quad (f2 over b).
    f2 m0[K * K], m1[K * K];
    {
        const f2* mb = (const f2*)(mask + (size_t)n * (K * K) * HOWO
                                        + (size_t)(2 * hb) * WO + 2 * c);
        #pragma unroll
        for (int i = 0; i < K * K; ++i) {
            m0[i] = mb[(size_t)i * (HOWO / 2)];            // a = 0
            m1[i] = mb[(size_t)i * (HOWO / 2) + WO / 2];   // a = 1
        }
    }

    // Staging geometry: halo positions tid, tid+256, tid+512 (if < POS).
    int off[3]; bool val[3];
    #pragma unroll
    for (int i = 0; i < 3; ++i) {
        int p  = tid + i * 256;
        int rr = p / LDS_C, cc = p - rr * LDS_C;
        int hs = h0 - 2 + rr;
        int ws = cc - 2;
        val[i] = (p < POS) && (hs >= 0) && (hs < H_) && (ws >= 0) && (ws < W_);
        off[i] = hs * W_ + ws;
    }

    // ONE 4-channel slab per buffer: 17408 B total -> ~6+ blocks/CU resident
    // (was 34.8 KB -> hard 4-block cap). More independent phase-streams per
    // CU to keep DS and HBM simultaneously fed.
    __shared__ float4 lds[2][POS];

    const float* fbase = feat + (size_t)n * C_ * HW;
    float*       obase = out  + (size_t)n * C_ * HOWO
                              + (size_t)(2 * hb) * WO + 2 * c;

    // Depth-1 staging, single register set, all indices static.
    float sreg[3][UC];
    auto stage_load = [&](int cbase) {
        const float* fp = fbase + (size_t)cbase * HW;
        #pragma unroll
        for (int i = 0; i < 3; ++i)
            #pragma unroll
            for (int u = 0; u < UC; ++u)
                sreg[i][u] = val[i] ? fp[u * HW + off[i]] : 0.f;
    };
    auto stage_write = [&](int buf) {
        #pragma unroll
        for (int i = 0; i < 3; ++i) {
            int p = tid + i * 256;
            if (p < POS)
                lds[buf][p] = make_float4(sreg[i][0], sreg[i][1],
                                          sreg[i][2], sreg[i][3]);
        }
    };

    stage_load(c0);
    stage_write(0);
    __syncthreads();

    const int rbase = r * LDS_C + c;

    for (int g = 0; g < NGROUP; ++g) {
        const int buf = g & 1;

        // T14: issue next group's global loads before compute.
        if (g + 1 < NGROUP) stage_load(c0 + (g + 1) * UC);

        const float4* Ls = &lds[buf][rbase];
        f2 a0[4], a1[4];
        #pragma unroll
        for (int u = 0; u < 4; ++u) { a0[u] = (f2)0.f; a1[u] = (f2)0.f; }
        #pragma unroll
        for (int ki = 0; ki < K; ++ki) {
            #pragma unroll
            for (int kj = 0; kj < K; ++kj) {
                float4 f  = Ls[ki * LDS_C + kj];   // 1 ds_read_b128 -> 16 FMA
                f2 w0m = m0[ki * K + kj];
                f2 w1m = m1[ki * K + kj];
                a0[0] += f.x * w0m;  a1[0] += f.x * w1m;
                a0[1] += f.y * w0m;  a1[1] += f.y * w1m;
                a0[2] += f.z * w0m;  a1[2] += f.z * w1m;
                a0[3] += f.w * w0m;  a1[3] += f.w * w1m;
            }
        }
        // One wave = one base row: each store covers a full aligned 512B
        // output row; block writes 8 consecutive rows per channel.
        #pragma unroll
        for (int u = 0; u < 4; ++u) {
            f2* op = (f2*)(obase + (size_t)(c0 + g * UC + u) * HOWO);
            __builtin_nontemporal_store(a0[u], op);            // row 2hb
            __builtin_nontemporal_store(a1[u], op + WO / 2);   // row 2hb+1
        }

        if (g + 1 < NGROUP) {
            stage_write(buf ^ 1);
            __syncthreads();
        }
    }
}

extern "C" void kernel_launch(void* const* d_in, const int* in_sizes, int n_in,
                              void* d_out, int out_size, void* d_ws, size_t ws_size,
                              hipStream_t stream) {
    const float* feat = (const float*)d_in[0];
    const float* mask = (const float*)d_in[1];
    float* out = (float*)d_out;

    dim3 grid(H_ / HB, N_ * (C_ / CCHUNK));  // (16, 64) = 1024 blocks
    dim3 block(256);
    carafe_row_kernel<<<grid, block, 0, stream>>>(feat, mask, out);
}

// Round 15
// 44.523 us; speedup vs baseline: 1.1552x; 1.0253x over previous
//
#include <hip/hip_runtime.h>

#define K 5
#define N_ 8
#define C_ 256
#define H_ 64
#define W_ 64
#define HW (H_ * W_)
#define HO 128
#define WO 128
#define HOWO (HO * WO)
#define HB 4              // base rows per block (full width)
#define CCHUNK 32         // channels per block
#define UC 8              // channels per stage group (2 float4 slabs)
#define NGROUP (CCHUNK / UC)      // 4
#define LDS_R (HB + K - 1)        // 8 halo rows
#define LDS_C 68                  // 64 cols + 2 pad each side (zero-filled)
#define POS (LDS_R * LDS_C)       // 544

typedef __attribute__((ext_vector_type(2))) float f2;

__global__ __launch_bounds__(256)
void carafe_row_kernel(const float* __restrict__ feat,
                       const float* __restrict__ mask,
                       float* __restrict__ out) {
    const int ht = blockIdx.x;       // 0..15
    const int zc = blockIdx.y;       // 0..63 (n*8 + chunk)
    const int n  = zc >> 3;
    const int c0 = (zc & 7) * CCHUNK;
    const int h0 = ht * HB;

    const int tid = threadIdx.x;
    const int r   = tid >> 6;        // 0..3  base row (one wave = one row)
    const int c   = tid & 63;        // 0..63 base col (full width)
    const int hb  = h0 + r;

    // Channel-invariant masks for this thread's 2x2 output quad (f2 over b).
    f2 m0[K * K], m1[K * K];
    {
        const f2* mb = (const f2*)(mask + (size_t)n * (K * K) * HOWO
                                        + (size_t)(2 * hb) * WO + 2 * c);
        #pragma unroll
        for (int i = 0; i < K * K; ++i) {
            m0[i] = mb[(size_t)i * (HOWO / 2)];            // a = 0
            m1[i] = mb[(size_t)i * (HOWO / 2) + WO / 2];   // a = 1
        }
    }

    // Staging geometry: halo positions tid, tid+256, tid+512 (if < POS).
    int off[3]; bool val[3];
    #pragma unroll
    for (int i = 0; i < 3; ++i) {
        int p  = tid + i * 256;
        int rr = p / LDS_C, cc = p - rr * LDS_C;
        int hs = h0 - 2 + rr;
        int ws = cc - 2;
        val[i] = (p < POS) && (hs >= 0) && (hs < H_) && (ws >= 0) && (ws < W_);
        off[i] = hs * W_ + ws;
    }

    // Channel-interleaved halo tile: [buf][slab of 4ch][pos] float4. 34816 B.
    __shared__ float4 lds[2][2][POS];

    const float* fbase = feat + (size_t)n * C_ * HW;
    float*       obase = out  + (size_t)n * C_ * HOWO
                              + (size_t)(2 * hb) * WO + 2 * c;

    // Depth-1 staging, single register set, all indices static.
    float sreg[3][UC];
    auto stage_load = [&](int cbase) {
        const float* fp = fbase + (size_t)cbase * HW;
        #pragma unroll
        for (int i = 0; i < 3; ++i)
            #pragma unroll
            for (int u = 0; u < UC; ++u)
                sreg[i][u] = val[i] ? fp[u * HW + off[i]] : 0.f;
    };
    auto stage_write = [&](int buf) {
        #pragma unroll
        for (int i = 0; i < 3; ++i) {
            int p = tid + i * 256;
            if (p < POS) {
                lds[buf][0][p] = make_float4(sreg[i][0], sreg[i][1],
                                             sreg[i][2], sreg[i][3]);
                lds[buf][1][p] = make_float4(sreg[i][4], sreg[i][5],
                                             sreg[i][6], sreg[i][7]);
            }
        }
    };

    stage_load(c0);
    stage_write(0);
    __syncthreads();

    const int rbase = r * LDS_C + c;

    for (int g = 0; g < NGROUP; ++g) {
        const int buf = g & 1;

        // T14: issue next group's global loads before compute.
        if (g + 1 < NGROUP) stage_load(c0 + (g + 1) * UC);

        #pragma unroll
        for (int ss = 0; ss < 2; ++ss) {
            const float4* Ls = &lds[buf][ss][rbase];
            f2 a0[4], a1[4];
            #pragma unroll
            for (int u = 0; u < 4; ++u) { a0[u] = (f2)0.f; a1[u] = (f2)0.f; }
            #pragma unroll
            for (int ki = 0; ki < K; ++ki) {
                #pragma unroll
                for (int kj = 0; kj < K; ++kj) {
                    float4 f  = Ls[ki * LDS_C + kj];   // 1 ds_read_b128 -> 16 FMA
                    f2 w0m = m0[ki * K + kj];
                    f2 w1m = m1[ki * K + kj];
                    a0[0] += f.x * w0m;  a1[0] += f.x * w1m;
                    a0[1] += f.y * w0m;  a1[1] += f.y * w1m;
                    a0[2] += f.z * w0m;  a1[2] += f.z * w1m;
                    a0[3] += f.w * w0m;  a1[3] += f.w * w1m;
                }
            }
            // PLAIN stores (the single variable vs R9): let L2 allocate and
            // write-combine the stream, as the 7 TB/s fill does.
            #pragma unroll
            for (int u = 0; u < 4; ++u) {
                f2* op = (f2*)(obase + (size_t)(c0 + g * UC + ss * 4 + u) * HOWO);
                op[0]      = a0[u];   // row 2hb
                op[WO / 2] = a1[u];   // row 2hb+1
            }
        }

        if (g + 1 < NGROUP) {
            stage_write(buf ^ 1);
            __syncthreads();
        }
    }
}

extern "C" void kernel_launch(void* const* d_in, const int* in_sizes, int n_in,
                              void* d_out, int out_size, void* d_ws, size_t ws_size,
                              hipStream_t stream) {
    const float* feat = (const float*)d_in[0];
    const float* mask = (const float*)d_in[1];
    float* out = (float*)d_out;

    dim3 grid(H_ / HB, N_ * (C_ / CCHUNK));  // (16, 64) = 1024 blocks
    dim3 block(256);
    carafe_row_kernel<<<grid, block, 0, stream>>>(feat, mask, out);
}